// Round 1
// baseline (126488.391 us; speedup 1.0000x reference)
//
#include <hip/hip_runtime.h>
#include <math.h>

// Problem constants
// B=32, T=512, IDIM=512, ODIM=80, L=256, DUNITS=1024, ATT=128, ACH=10, AK=31, PRE=256, POST=512

__device__ __forceinline__ float sigm(float x){ return 1.0f/(1.0f+__expf(-x)); }

// ---------------- workspace layout (floats) ----------------
// OFF_ENC  : 0         (2097152)  enc_proj (B,T,ATT)
// OFF_AW   : 2097152   (16384)    aw (B,T)
// OFF_E    : 2113536   (16384)    e  (B,T)
// OFF_DEC  : 2129920   (4096)     dec (B,ATT)
// OFF_XC   : 2134016   (24576)    xc (B,768)  [att_c | prenet]
// OFF_Z0   : 2158592   (65536)    z0 ping-pong (2,B,1024)
// OFF_Z1   : 2224128   (65536)    z1 ping-pong
// OFF_C0   : 2289664   (32768)
// OFF_C1   : 2322432   (32768)
// OFF_FWT  : 2355200   (81920)    feat_w transposed (80,1024)
// OFF_WDT  : 2437120   (131072)   w_dec transposed (128,1024)
// OFF_OUTS : 2568192   (655360)   outs_ws (B,80,L)
// OFF_PN1  : 3223552   (4194304)  postnet buf (B,512,L)  [word 0 doubles as grid-barrier counter during the loop]
// OFF_PN2  : 7417856   (4194304)
// OFF_BSC  : 11612160  (512)
// OFF_BSH  : 11612672  (512)

// ---------------- grid barrier (arrive + spin, device scope) ----------------
// All 256 blocks are co-resident by construction (256 blocks, 256 thr, ~10.6KB LDS,
// capacity >= 2 blocks/CU on 256 CUs), so spinning is deadlock-free.
__device__ __forceinline__ void gbar(unsigned* cnt, unsigned target) {
  __syncthreads();
  if (threadIdx.x == 0) {
    __threadfence();  // agent release: write back this XCD's dirty L2
    __hip_atomic_fetch_add(cnt, 1u, __ATOMIC_RELAXED, __HIP_MEMORY_SCOPE_AGENT);
    while (__hip_atomic_load(cnt, __ATOMIC_RELAXED, __HIP_MEMORY_SCOPE_AGENT) < target)
      __builtin_amdgcn_s_sleep(2);
    __threadfence();  // agent acquire: invalidate stale lines
  }
  __syncthreads();
}

// ---------------- init: zero states, aw0, weight transposes, ylens, barrier ----------------
__global__ void k_init(float* __restrict__ z0, float* __restrict__ c0,
                       float* __restrict__ z1, float* __restrict__ c1,
                       float* __restrict__ aw, float* __restrict__ fw_t, float* __restrict__ wdec_t,
                       const float* __restrict__ feat_w, const float* __restrict__ w_dec,
                       const int* __restrict__ hlens, const int* __restrict__ ylens,
                       float* __restrict__ d_out, unsigned* __restrict__ barcnt) {
  int i = blockIdx.x*256 + threadIdx.x;
  if (i < 32768) {
    z0[i]=0.f; c0[i]=0.f; z1[i]=0.f; c1[i]=0.f;
  } else if (i < 49152) {
    int j = i - 32768; int b = j >> 9; int t = j & 511;
    int hl = hlens[b];
    aw[j] = (t < hl) ? 1.0f/(float)hl : 0.f;
  } else if (i < 131072) {
    int j = i - 49152; int od = j >> 10, k = j & 1023;
    fw_t[j] = feat_w[k*80 + od];
  } else if (i < 262144) {
    int j = i - 131072; int a = j >> 10, k = j & 1023;
    wdec_t[j] = w_dec[k*128 + a];
  } else if (i < 262176) {
    int b = i - 262144;
    d_out[663552 + b] = (float)ylens[b];
  } else if (i == 262176) {
    *barcnt = 0u;
  }
}

// ---------------- enc_proj = hs @ w_enc + b_enc ----------------
__global__ void k_encproj(const float* __restrict__ hs, const float* __restrict__ w_enc,
                          const float* __restrict__ b_enc, float* __restrict__ enc_proj) {
  __shared__ float hsl[16*512];
  int b = blockIdx.x, t0 = blockIdx.y*16;
  int tid = threadIdx.x;  // 256
  for (int i = tid; i < 16*512; i += 256)
    hsl[i] = hs[(size_t)(b*512 + t0 + (i>>9))*512 + (i&511)];
  __syncthreads();
  int a = tid & 127, tq = tid >> 7;
  float acc[8];
  #pragma unroll
  for (int u=0;u<8;++u) acc[u]=0.f;
  for (int d=0; d<512; ++d) {
    float w = w_enc[d*128 + a];
    #pragma unroll
    for (int u=0;u<8;++u) acc[u] += hsl[(tq*8+u)*512 + d]*w;
  }
  float be = b_enc[a];
  #pragma unroll
  for (int u=0;u<8;++u)
    enc_proj[(size_t)(b*512 + t0 + tq*8 + u)*128 + a] = acc[u] + be;
}

// ---------------- LSTM block body (identical math/order to old k_lstm) ----------------
__device__ __forceinline__ void lstm_block(
    const float* __restrict__ xin, int xK, const float* __restrict__ wih,
    const float* __restrict__ hin, const float* __restrict__ whh,
    const float* __restrict__ bias, float* __restrict__ cst, float* __restrict__ hnew,
    int gid, int tid, float* __restrict__ sm) {
  float* xs   = sm;          // 64*33 = 2112
  float* gbuf = sm + 2112;   // 16*33 = 528
  int u0 = gid*4;
  int b = tid & 31, jq = tid >> 5;
  int jj0 = jq*2;
  int gate = jj0 >> 2;
  int uo0 = jj0 & 3;
  int j0 = gate*1024 + u0 + uo0;
  float acc0 = bias[j0], acc1 = bias[j0 + 1];
  const float* w0 = wih + (size_t)j0*xK;
  const float* w1 = w0 + xK;
  for (int k0 = 0; k0 < xK; k0 += 64) {
    __syncthreads();
    for (int i = tid; i < 32*64; i += 256) {
      int bb = i >> 6, kk = i & 63;
      xs[kk*33 + bb] = xin[bb*xK + k0 + kk];
    }
    __syncthreads();
    #pragma unroll
    for (int kk = 0; kk < 64; kk += 4) {
      float4 a0 = *(const float4*)(w0 + k0 + kk);
      float4 a1 = *(const float4*)(w1 + k0 + kk);
      float x0 = xs[(kk+0)*33 + b];
      float x1 = xs[(kk+1)*33 + b];
      float x2 = xs[(kk+2)*33 + b];
      float x3 = xs[(kk+3)*33 + b];
      acc0 += a0.x*x0 + a0.y*x1 + a0.z*x2 + a0.w*x3;
      acc1 += a1.x*x0 + a1.y*x1 + a1.z*x2 + a1.w*x3;
    }
  }
  const float* v0 = whh + (size_t)j0*1024;
  const float* v1 = v0 + 1024;
  for (int k0 = 0; k0 < 1024; k0 += 64) {
    __syncthreads();
    for (int i = tid; i < 32*64; i += 256) {
      int bb = i >> 6, kk = i & 63;
      xs[kk*33 + bb] = hin[bb*1024 + k0 + kk];
    }
    __syncthreads();
    #pragma unroll
    for (int kk = 0; kk < 64; kk += 4) {
      float4 a0 = *(const float4*)(v0 + k0 + kk);
      float4 a1 = *(const float4*)(v1 + k0 + kk);
      float x0 = xs[(kk+0)*33 + b];
      float x1 = xs[(kk+1)*33 + b];
      float x2 = xs[(kk+2)*33 + b];
      float x3 = xs[(kk+3)*33 + b];
      acc0 += a0.x*x0 + a0.y*x1 + a0.z*x2 + a0.w*x3;
      acc1 += a1.x*x0 + a1.y*x1 + a1.z*x2 + a1.w*x3;
    }
  }
  gbuf[jj0*33 + b] = acc0;
  gbuf[(jj0+1)*33 + b] = acc1;
  __syncthreads();
  if (tid < 128) {
    int b2 = tid & 31, uo = tid >> 5;
    float gi = gbuf[(0*4 + uo)*33 + b2];
    float gf = gbuf[(1*4 + uo)*33 + b2];
    float gg = gbuf[(2*4 + uo)*33 + b2];
    float go = gbuf[(3*4 + uo)*33 + b2];
    int u = u0 + uo;
    float c_old = cst[b2*1024 + u];
    float c_new = sigm(gf)*c_old + sigm(gi)*tanhf(gg);
    float h = sigm(go)*tanhf(c_new);
    cst[b2*1024 + u] = c_new;
    hnew[b2*1024 + u] = h;
  }
}

// ---------------- persistent decoder loop: 256 steps, 5 grid barriers/step ----------------
__global__ __launch_bounds__(256, 1) void k_loop(
    const float* __restrict__ hs, const int* __restrict__ hlens,
    const float* __restrict__ enc_proj, const float* __restrict__ loc_k,
    const float* __restrict__ w_loc, const float* __restrict__ gvec,
    const float* __restrict__ pre_w1, const float* __restrict__ pre_b1,
    const float* __restrict__ pre_w2, const float* __restrict__ pre_b2,
    const float* __restrict__ l0_wih, const float* __restrict__ l0_whh, const float* __restrict__ l0_b,
    const float* __restrict__ l1_wih, const float* __restrict__ l1_whh, const float* __restrict__ l1_b,
    const float* __restrict__ fw_t, const float* __restrict__ feat_b,
    const float* __restrict__ prob_w, const float* __restrict__ prob_b,
    const float* __restrict__ wdec_t,
    float* __restrict__ aw, float* __restrict__ e_buf, float* __restrict__ dec,
    float* __restrict__ xc, float* __restrict__ z0buf, float* __restrict__ c0,
    float* __restrict__ z1buf, float* __restrict__ c1,
    float* __restrict__ outs_ws, float* __restrict__ probs_out,
    unsigned* __restrict__ barcnt) {
  __shared__ float sm[2688];
  const int gid = blockIdx.x;
  const int tid = threadIdx.x;
  unsigned nbar = 0;

  for (int s = 0; s < 256; ++s) {
    const int p = s & 1;
    const float* z0r = z0buf + p*32768;
    float*       z0w = z0buf + (1-p)*32768;
    const float* z1r = z1buf + p*32768;
    float*       z1w = z1buf + (1-p)*32768;

    // ---------- phase A: feat/prob/prenet (blocks 0..31) | dec GEMM (blocks 32..63) ----------
    if (gid < 32) {
      const int b = gid;
      float* zs   = sm;         // 1024
      float* prev = sm + 1024;  // 80
      float* h1s  = sm + 1104;  // 256
      for (int i = tid; i < 1024; i += 256) zs[i] = z1r[b*1024 + i];
      __syncthreads();
      if (tid < 80) {
        const float4* wp = (const float4*)(fw_t + tid*1024);
        const float4* zp = (const float4*)zs;
        float acc = feat_b[tid];
        for (int k4 = 0; k4 < 256; ++k4) {
          float4 w = wp[k4]; float4 z = zp[k4];
          acc += w.x*z.x + w.y*z.y + w.z*z.z + w.w*z.w;
        }
        prev[tid] = acc;
        if (s > 0) outs_ws[(b*80 + tid)*256 + (s-1)] = acc;
      } else if (tid == 80) {
        const float4* wp = (const float4*)prob_w;
        const float4* zp = (const float4*)zs;
        float acc = prob_b[0];
        for (int k4 = 0; k4 < 256; ++k4) {
          float4 w = wp[k4]; float4 z = zp[k4];
          acc += w.x*z.x + w.y*z.y + w.z*z.z + w.w*z.w;
        }
        if (s > 0) probs_out[b*256 + (s-1)] = acc;
      }
      __syncthreads();
      {
        float acc = pre_b1[tid];
        for (int k = 0; k < 80; ++k) acc += prev[k]*pre_w1[k*256 + tid];
        h1s[tid] = fmaxf(acc, 0.f);
      }
      __syncthreads();
      {
        float acc = pre_b2[tid];
        for (int k = 0; k < 256; ++k) acc += h1s[k]*pre_w2[k*256 + tid];
        xc[b*768 + 512 + tid] = fmaxf(acc, 0.f);
      }
    } else if (gid < 64) {
      const int b = gid - 32;
      float* zs   = sm;         // 1024
      float* dred = sm + 1024;  // 256
      for (int i = tid; i < 1024; i += 256) zs[i] = z0r[b*1024 + i];
      __syncthreads();
      const int a = tid & 127, h = tid >> 7;
      const float4* wp = (const float4*)(wdec_t + a*1024 + h*512);
      const float4* zp = (const float4*)(zs + h*512);
      float acc = 0.f;
      for (int k4 = 0; k4 < 128; ++k4) {
        float4 w = wp[k4]; float4 z = zp[k4];
        acc += w.x*z.x + w.y*z.y + w.z*z.z + w.w*z.w;
      }
      dred[tid] = acc;
      __syncthreads();
      if (tid < 128) dec[b*128 + tid] = dred[tid] + dred[tid + 128];
    }
    gbar(barcnt, 256u*(++nbar));

    // ---------- phase B: attention energies, block = (b, 64-t chunk) ----------
    {
      const int b = gid >> 3;
      const int t0 = (gid & 7)*64;
      float* awin = sm;        // 94
      float* locl = sm + 96;   // 640  locl[c*64+tt]
      float* redB = sm + 736;  // 4*32
      if (tid < 94) {
        int idx = t0 - 15 + tid;
        awin[tid] = (idx >= 0 && idx < 512) ? aw[b*512 + idx] : 0.f;
      }
      __syncthreads();
      for (int i = tid; i < 640; i += 256) {
        int c = i >> 6, tt = i & 63;
        float sacc = 0.f;
        #pragma unroll
        for (int k = 0; k < 31; ++k) sacc += awin[tt + k]*loc_k[c*31 + k];
        locl[i] = sacc;
      }
      __syncthreads();
      const int a = tid & 127, th = tid >> 7, wv = tid >> 6;
      const float dec_a = dec[b*128 + a];
      const float gv = gvec[a];
      float wl[10];
      #pragma unroll
      for (int c = 0; c < 10; ++c) wl[c] = w_loc[c*128 + a];
      for (int tt = 0; tt < 32; ++tt) {
        const int tl = th*32 + tt;
        float sv = enc_proj[(size_t)(b*512 + t0 + tl)*128 + a] + dec_a;
        #pragma unroll
        for (int c = 0; c < 10; ++c) sv += locl[c*64 + tl]*wl[c];
        float v = tanhf(sv)*gv;
        #pragma unroll
        for (int off = 32; off; off >>= 1) v += __shfl_down(v, off);
        if ((tid & 63) == 0) redB[wv*32 + tt] = v;
      }
      __syncthreads();
      if (tid < 64) {
        const int t = t0 + tid;
        float ee = (tid < 32) ? (redB[tid] + redB[32 + tid])
                              : (redB[64 + (tid - 32)] + redB[96 + (tid - 32)]);
        e_buf[b*512 + t] = (t < hlens[b]) ? ee : -1e30f;
      }
    }
    gbar(barcnt, 256u*(++nbar));

    // ---------- phase C: softmax + context, block = (b, 64-d chunk), t split over 4 waves ----------
    {
      const int b = gid >> 3, dc = gid & 7;
      float* aws  = sm;        // 512
      float* red8 = sm + 512;  // 8
      float* cred = sm + 520;  // 256
      const float e0 = e_buf[b*512 + tid];
      const float e1 = e_buf[b*512 + 256 + tid];
      float m = fmaxf(e0, e1);
      #pragma unroll
      for (int off = 32; off; off >>= 1) m = fmaxf(m, __shfl_xor(m, off));
      if ((tid & 63) == 0) red8[tid >> 6] = m;
      __syncthreads();
      m = fmaxf(fmaxf(red8[0], red8[1]), fmaxf(red8[2], red8[3]));
      const float p0 = __expf(e0 - m), p1 = __expf(e1 - m);
      float ssum = p0 + p1;
      #pragma unroll
      for (int off = 32; off; off >>= 1) ssum += __shfl_xor(ssum, off);
      if ((tid & 63) == 0) red8[4 + (tid >> 6)] = ssum;
      __syncthreads();
      const float inv = 1.0f/(red8[4] + red8[5] + red8[6] + red8[7]);
      const float a0 = p0*inv, a1 = p1*inv;
      aws[tid] = a0; aws[tid + 256] = a1;
      if (dc == 0) { aw[b*512 + tid] = a0; aw[b*512 + 256 + tid] = a1; }
      __syncthreads();
      const int d = dc*64 + (tid & 63), w = tid >> 6;
      const float* hp  = hs + (size_t)(b*512 + w*128)*512 + d;
      const float* awp = aws + w*128;
      float acc = 0.f;
      #pragma unroll 8
      for (int t = 0; t < 128; ++t) acc += awp[t]*hp[(size_t)t*512];
      cred[w*64 + (tid & 63)] = acc;
      __syncthreads();
      if (tid < 64)
        xc[b*768 + dc*64 + tid] = cred[tid] + cred[64 + tid] + cred[128 + tid] + cred[192 + tid];
    }
    gbar(barcnt, 256u*(++nbar));

    // ---------- phase D: lstm0 ----------
    lstm_block(xc, 768, l0_wih, z0r, l0_whh, l0_b, c0, z0w, gid, tid, sm);
    gbar(barcnt, 256u*(++nbar));

    // ---------- phase E: lstm1 ----------
    lstm_block(z0w, 1024, l1_wih, z1r, l1_whh, l1_b, c1, z1w, gid, tid, sm);
    gbar(barcnt, 256u*(++nbar));
  }

  // ---------- tail: outs/probs for idx 255 from final z1 (parity-0 buffer) ----------
  if (gid < 32) {
    const int b = gid;
    float* zs = sm;
    for (int i = tid; i < 1024; i += 256) zs[i] = z1buf[b*1024 + i];
    __syncthreads();
    if (tid < 80) {
      const float4* wp = (const float4*)(fw_t + tid*1024);
      const float4* zp = (const float4*)zs;
      float acc = feat_b[tid];
      for (int k4 = 0; k4 < 256; ++k4) {
        float4 w = wp[k4]; float4 z = zp[k4];
        acc += w.x*z.x + w.y*z.y + w.z*z.z + w.w*z.w;
      }
      outs_ws[(b*80 + tid)*256 + 255] = acc;
    } else if (tid == 80) {
      const float4* wp = (const float4*)prob_w;
      const float4* zp = (const float4*)zs;
      float acc = prob_b[0];
      for (int k4 = 0; k4 < 256; ++k4) {
        float4 w = wp[k4]; float4 z = zp[k4];
        acc += w.x*z.x + w.y*z.y + w.z*z.z + w.w*z.w;
      }
      probs_out[b*256 + 255] = acc;
    }
  }
}

// ---------------- postnet conv1d (k=5, pad=2), optional fused residual+transpose ----------------
__global__ void k_conv(const float* __restrict__ in, const float* __restrict__ wk,
                       int CI, int CO, float* __restrict__ out,
                       const float* __restrict__ resid, float* __restrict__ final_out) {
  int b = blockIdx.x, coT = blockIdx.y, lT = blockIdx.z;
  int l0 = lT*64;
  int tid = threadIdx.x;
  int lq = tid & 15, coq = tid >> 4;
  __shared__ float xs[16*68];
  __shared__ float wt[64*81];
  float acc[4][4];
  #pragma unroll
  for (int m = 0; m < 4; ++m)
    #pragma unroll
    for (int li = 0; li < 4; ++li) acc[m][li] = 0.f;
  int coBase = coT*64 + coq*4;
  for (int cc0 = 0; cc0 < CI; cc0 += 16) {
    __syncthreads();
    for (int i = tid; i < 16*68; i += 256) {
      int ci = i/68, pos = i - ci*68;
      int gl = l0 - 2 + pos;
      xs[i] = (gl >= 0 && gl < 256) ? in[((size_t)b*CI + cc0 + ci)*256 + gl] : 0.f;
    }
    for (int i = tid; i < 64*80; i += 256) {
      int co_i = i/80, rem = i - co_i*80;
      int cog = coT*64 + co_i;
      float w = (cog < CO) ? wk[(size_t)cog*CI*5 + (size_t)cc0*5 + rem] : 0.f;
      wt[co_i*81 + rem] = w;
    }
    __syncthreads();
    #pragma unroll 2
    for (int ci = 0; ci < 16; ++ci) {
      float4 xa = *(const float4*)&xs[ci*68 + lq*4];
      float4 xb = *(const float4*)&xs[ci*68 + lq*4 + 4];
      float x8[8] = {xa.x, xa.y, xa.z, xa.w, xb.x, xb.y, xb.z, xb.w};
      #pragma unroll
      for (int kk = 0; kk < 5; ++kk) {
        float w0 = wt[(coq*4+0)*81 + ci*5 + kk];
        float w1 = wt[(coq*4+1)*81 + ci*5 + kk];
        float w2 = wt[(coq*4+2)*81 + ci*5 + kk];
        float w3 = wt[(coq*4+3)*81 + ci*5 + kk];
        #pragma unroll
        for (int li = 0; li < 4; ++li) {
          float xv = x8[kk + li];
          acc[0][li] += w0*xv; acc[1][li] += w1*xv;
          acc[2][li] += w2*xv; acc[3][li] += w3*xv;
        }
      }
    }
  }
  if (final_out) {
    #pragma unroll
    for (int m = 0; m < 4; ++m) {
      int co = coBase + m;
      if (co < CO) {
        #pragma unroll
        for (int li = 0; li < 4; ++li) {
          int l = l0 + lq*4 + li;
          final_out[(size_t)(b*256 + l)*80 + co] =
              acc[m][li] + resid[((size_t)b*80 + co)*256 + l];
        }
      }
    }
  } else {
    #pragma unroll
    for (int m = 0; m < 4; ++m) {
      int co = coBase + m;
      if (co < CO) {
        float4 v = {acc[m][0], acc[m][1], acc[m][2], acc[m][3]};
        *(float4*)&out[((size_t)b*CO + co)*256 + l0 + lq*4] = v;
      }
    }
  }
}

// ---------------- BN train-mode stats (per channel over B,L) ----------------
__global__ void k_bnstats(const float* __restrict__ x, const float* __restrict__ g,
                          const float* __restrict__ bt, float* __restrict__ scale,
                          float* __restrict__ shift) {
  int c = blockIdx.x;
  int tid = threadIdx.x;  // 256
  float s = 0.f, s2 = 0.f;
  for (int i = tid; i < 8192; i += 256) {
    int bb = i >> 8, l = i & 255;
    float v = x[((size_t)bb*512 + c)*256 + l];
    s += v; s2 += v*v;
  }
  __shared__ float rs[256], rs2[256];
  rs[tid] = s; rs2[tid] = s2;
  __syncthreads();
  for (int st = 128; st; st >>= 1) {
    if (tid < st) { rs[tid] += rs[tid + st]; rs2[tid] += rs2[tid + st]; }
    __syncthreads();
  }
  if (tid == 0) {
    float m = rs[0]/8192.f;
    float var = rs2[0]/8192.f - m*m;
    float inv = rsqrtf(var + 1e-5f);
    float sc = g[c]*inv;
    scale[c] = sc;
    shift[c] = bt[c] - m*sc;
  }
}

__global__ void k_bnapply(float* __restrict__ x, const float* __restrict__ scale,
                          const float* __restrict__ shift) {
  int i = blockIdx.x*256 + threadIdx.x;
  if (i < 32*512*256) {
    int c = (i >> 8) & 511;
    x[i] = tanhf(scale[c]*x[i] + shift[c]);
  }
}

// ---------------- launcher ----------------
extern "C" void kernel_launch(void* const* d_in, const int* in_sizes, int n_in,
                              void* d_out, int out_size, void* d_ws, size_t ws_size,
                              hipStream_t stream) {
  const float* hs       = (const float*)d_in[0];
  const int*   hlens    = (const int*)d_in[1];
  const int*   ylens    = (const int*)d_in[3];
  const float* w_enc    = (const float*)d_in[4];
  const float* b_enc    = (const float*)d_in[5];
  const float* w_dec    = (const float*)d_in[6];
  const float* loc_k    = (const float*)d_in[7];
  const float* w_loc    = (const float*)d_in[8];
  const float* gvec     = (const float*)d_in[9];
  const float* pre_w1   = (const float*)d_in[10];
  const float* pre_b1   = (const float*)d_in[11];
  const float* pre_w2   = (const float*)d_in[12];
  const float* pre_b2   = (const float*)d_in[13];
  const float* l0_wih   = (const float*)d_in[14];
  const float* l0_whh   = (const float*)d_in[15];
  const float* l0_b     = (const float*)d_in[16];
  const float* l1_wih   = (const float*)d_in[17];
  const float* l1_whh   = (const float*)d_in[18];
  const float* l1_b     = (const float*)d_in[19];
  const float* feat_w   = (const float*)d_in[20];
  const float* feat_b   = (const float*)d_in[21];
  const float* prob_w   = (const float*)d_in[22];
  const float* prob_b   = (const float*)d_in[23];
  const float* post_k1  = (const float*)d_in[24];
  const float* post_k2  = (const float*)d_in[25];
  const float* post_k3  = (const float*)d_in[26];
  const float* post_k4  = (const float*)d_in[27];
  const float* post_k5  = (const float*)d_in[28];
  const float* bn_g1 = (const float*)d_in[29]; const float* bn_b1 = (const float*)d_in[30];
  const float* bn_g2 = (const float*)d_in[31]; const float* bn_b2 = (const float*)d_in[32];
  const float* bn_g3 = (const float*)d_in[33]; const float* bn_b3 = (const float*)d_in[34];
  const float* bn_g4 = (const float*)d_in[35]; const float* bn_b4 = (const float*)d_in[36];

  float* ws = (float*)d_ws;
  float* enc_proj = ws + 0;
  float* aw       = ws + 2097152;
  float* e        = ws + 2113536;
  float* dec      = ws + 2129920;
  float* xc       = ws + 2134016;
  float* z0       = ws + 2158592;   // 2 x 32768
  float* z1       = ws + 2224128;   // 2 x 32768
  float* c0       = ws + 2289664;
  float* c1       = ws + 2322432;
  float* fw_t     = ws + 2355200;
  float* wdec_t   = ws + 2437120;
  float* outs_ws  = ws + 2568192;
  float* pn1      = ws + 3223552;
  float* pn2      = ws + 7417856;
  float* bsc      = ws + 11612160;
  float* bsh      = ws + 11612672;
  unsigned* barcnt = (unsigned*)pn1;   // pn1 unused until after the loop

  float* outp  = (float*)d_out;            // outs (B,L,80)
  float* probp = outp + 655360;            // probs (B,L)

  k_init<<<1025, 256, 0, stream>>>(z0, c0, z1, c1, aw, fw_t, wdec_t,
                                   feat_w, w_dec, hlens, ylens, outp, barcnt);
  k_encproj<<<dim3(32, 32), 256, 0, stream>>>(hs, w_enc, b_enc, enc_proj);

  // the entire 256-step recurrence: one persistent kernel, 5 grid barriers/step
  k_loop<<<256, 256, 0, stream>>>(hs, hlens, enc_proj, loc_k, w_loc, gvec,
                                  pre_w1, pre_b1, pre_w2, pre_b2,
                                  l0_wih, l0_whh, l0_b, l1_wih, l1_whh, l1_b,
                                  fw_t, feat_b, prob_w, prob_b, wdec_t,
                                  aw, e, dec, xc, z0, c0, z1, c1,
                                  outs_ws, probp, barcnt);

  // postnet
  k_conv<<<dim3(32, 8, 4), 256, 0, stream>>>(outs_ws, post_k1, 80, 512, pn1, nullptr, nullptr);
  k_bnstats<<<512, 256, 0, stream>>>(pn1, bn_g1, bn_b1, bsc, bsh);
  k_bnapply<<<16384, 256, 0, stream>>>(pn1, bsc, bsh);

  k_conv<<<dim3(32, 8, 4), 256, 0, stream>>>(pn1, post_k2, 512, 512, pn2, nullptr, nullptr);
  k_bnstats<<<512, 256, 0, stream>>>(pn2, bn_g2, bn_b2, bsc, bsh);
  k_bnapply<<<16384, 256, 0, stream>>>(pn2, bsc, bsh);

  k_conv<<<dim3(32, 8, 4), 256, 0, stream>>>(pn2, post_k3, 512, 512, pn1, nullptr, nullptr);
  k_bnstats<<<512, 256, 0, stream>>>(pn1, bn_g3, bn_b3, bsc, bsh);
  k_bnapply<<<16384, 256, 0, stream>>>(pn1, bsc, bsh);

  k_conv<<<dim3(32, 8, 4), 256, 0, stream>>>(pn1, post_k4, 512, 512, pn2, nullptr, nullptr);
  k_bnstats<<<512, 256, 0, stream>>>(pn2, bn_g4, bn_b4, bsc, bsh);
  k_bnapply<<<16384, 256, 0, stream>>>(pn2, bsc, bsh);

  k_conv<<<dim3(32, 2, 4), 256, 0, stream>>>(pn2, post_k5, 512, 80, pn1, outs_ws, outp);
}

// Round 2
// 62364.514 us; speedup vs baseline: 2.0282x; 2.0282x over previous
//
#include <hip/hip_runtime.h>
#include <math.h>

// Problem constants
// B=32, T=512, IDIM=512, ODIM=80, L=256, DUNITS=1024, ATT=128, ACH=10, AK=31, PRE=256, POST=512

__device__ __forceinline__ float sigm(float x){ return 1.0f/(1.0f+__expf(-x)); }

// ---------------- workspace layout (floats) ----------------
// OFF_ENC  : 0         (2097152)  enc_proj (B,T,ATT)
// OFF_AW   : 2097152   (16384)    aw (B,T)
// OFF_E    : 2113536   (16384)    e  (B,T)
// OFF_DEC  : 2129920   (4096)     dec (B,ATT)
// OFF_XC   : 2134016   (24576)    xc (B,768)  [att_c | prenet]
// OFF_Z0   : 2158592   (65536)    z0 ping-pong (2,B,1024)
// OFF_Z1   : 2224128   (65536)    z1 ping-pong
// OFF_C0   : 2289664   (32768)
// OFF_C1   : 2322432   (32768)
// OFF_FWT  : 2355200   (81920)    feat_w transposed (80,1024)
// OFF_WDT  : 2437120   (131072)   w_dec transposed (128,1024)
// OFF_OUTS : 2568192   (655360)   outs_ws (B,80,L)
// OFF_PN1  : 3223552   (4194304)  postnet buf (B,512,L)
// OFF_PN2  : 7417856   (4194304)
// OFF_BSC  : 11612160  (512)
// OFF_BSH  : 11612672  (512)

// ---------------- init: zero states, aw0, dec0, weight transposes, ylens ----------------
__global__ void k_init(float* __restrict__ z0, float* __restrict__ c0,
                       float* __restrict__ z1, float* __restrict__ c1,
                       float* __restrict__ aw, float* __restrict__ fw_t, float* __restrict__ wdec_t,
                       float* __restrict__ dec,
                       const float* __restrict__ feat_w, const float* __restrict__ w_dec,
                       const int* __restrict__ hlens, const int* __restrict__ ylens,
                       float* __restrict__ d_out) {
  int i = blockIdx.x*256 + threadIdx.x;
  if (i < 32768) {
    z0[i]=0.f; c0[i]=0.f; z1[i]=0.f; c1[i]=0.f;
  } else if (i < 49152) {
    int j = i - 32768; int b = j >> 9; int t = j & 511;
    int hl = hlens[b];
    aw[j] = (t < hl) ? 1.0f/(float)hl : 0.f;
  } else if (i < 131072) {
    int j = i - 49152; int od = j >> 10, k = j & 1023;
    fw_t[j] = feat_w[k*80 + od];
  } else if (i < 262144) {
    int j = i - 131072; int a = j >> 10, k = j & 1023;
    wdec_t[j] = w_dec[k*128 + a];
  } else if (i < 262176) {
    int b = i - 262144;
    d_out[663552 + b] = (float)ylens[b];
  } else if (i < 266272) {
    dec[i - 262176] = 0.f;   // dec for step 0 (z0 = 0)
  }
}

// ---------------- enc_proj = hs @ w_enc + b_enc ----------------
__global__ void k_encproj(const float* __restrict__ hs, const float* __restrict__ w_enc,
                          const float* __restrict__ b_enc, float* __restrict__ enc_proj) {
  __shared__ float hsl[16*512];
  int b = blockIdx.x, t0 = blockIdx.y*16;
  int tid = threadIdx.x;  // 256
  for (int i = tid; i < 16*512; i += 256)
    hsl[i] = hs[(size_t)(b*512 + t0 + (i>>9))*512 + (i&511)];
  __syncthreads();
  int a = tid & 127, tq = tid >> 7;
  float acc[8];
  #pragma unroll
  for (int u=0;u<8;++u) acc[u]=0.f;
  for (int d=0; d<512; ++d) {
    float w = w_enc[d*128 + a];
    #pragma unroll
    for (int u=0;u<8;++u) acc[u] += hsl[(tq*8+u)*512 + d]*w;
  }
  float be = b_enc[a];
  #pragma unroll
  for (int u=0;u<8;++u)
    enc_proj[(size_t)(b*512 + t0 + tq*8 + u)*128 + a] = acc[u] + be;
}

// ---------------- merged: step_a (feat/prob/prenet, blocks 0..31) + att_e (blocks 32..2079) ----------------
__global__ __launch_bounds__(128) void k_ae(
    const float* __restrict__ z1_rd, const float* __restrict__ fw_t, const float* __restrict__ feat_b,
    const float* __restrict__ prob_w, const float* __restrict__ prob_b,
    const float* __restrict__ pre_w1, const float* __restrict__ pre_b1,
    const float* __restrict__ pre_w2, const float* __restrict__ pre_b2,
    float* __restrict__ outs_ws, float* __restrict__ probs_out, float* __restrict__ xc,
    const float* __restrict__ aw, const float* __restrict__ loc_k,
    const float* __restrict__ w_loc, const float* __restrict__ gvec,
    const float* __restrict__ enc_proj, const float* __restrict__ dec,
    const int* __restrict__ hlens, float* __restrict__ e_out,
    int store_idx, int mode) {
  int tid = threadIdx.x;  // 128
  if (blockIdx.x < 32) {
    // ---- step_a: out/prob from z1, prenet ----
    __shared__ float zs[1024];
    __shared__ float prev[80];
    __shared__ float h1s[256];
    int b = blockIdx.x;
    for (int i = tid; i < 1024; i += 128) zs[i] = z1_rd[b*1024 + i];
    __syncthreads();
    if (tid < 80) {
      const float4* wp = (const float4*)(fw_t + tid*1024);
      float acc = feat_b[tid];
      for (int k4 = 0; k4 < 256; ++k4) {
        float4 w = wp[k4];
        acc += zs[k4*4+0]*w.x + zs[k4*4+1]*w.y + zs[k4*4+2]*w.z + zs[k4*4+3]*w.w;
      }
      prev[tid] = acc;
      if (store_idx >= 0) outs_ws[(b*80 + tid)*256 + store_idx] = acc;
    } else if (tid == 80) {
      const float4* wp = (const float4*)prob_w;
      float acc = prob_b[0];
      for (int k4 = 0; k4 < 256; ++k4) {
        float4 w = wp[k4];
        acc += zs[k4*4+0]*w.x + zs[k4*4+1]*w.y + zs[k4*4+2]*w.z + zs[k4*4+3]*w.w;
      }
      if (store_idx >= 0) probs_out[b*256 + store_idx] = acc;
    }
    if (mode == 1) return;  // uniform branch: final out/prob only
    __syncthreads();
    // prenet layer 1: (80 -> 256)
    for (int j = tid; j < 256; j += 128) {
      float acc = pre_b1[j];
      for (int k = 0; k < 80; ++k) acc += prev[k]*pre_w1[k*256 + j];
      h1s[j] = fmaxf(acc, 0.f);
    }
    __syncthreads();
    // prenet layer 2: (256 -> 256)
    for (int j = tid; j < 256; j += 128) {
      float acc = pre_b2[j];
      for (int k = 0; k < 256; ++k) acc += h1s[k]*pre_w2[k*256 + j];
      xc[b*768 + 512 + j] = fmaxf(acc, 0.f);
    }
  } else {
    // ---- att_e: energies for 8 t positions ----
    int bx = blockIdx.x - 32;
    int b = bx >> 6;
    int t0 = (bx & 63)*8;
    __shared__ float awin[38];
    __shared__ float locl[10][8];
    __shared__ float red[2][8];
    if (tid < 38) {
      int idx = t0 - 15 + tid;
      awin[tid] = (idx >= 0 && idx < 512) ? aw[b*512 + idx] : 0.f;
    }
    __syncthreads();
    if (tid < 80) {
      int c = tid >> 3, tt = tid & 7;
      float s = 0.f;
      #pragma unroll
      for (int k = 0; k < 31; ++k) s += awin[tt + k]*loc_k[c*31 + k];
      locl[c][tt] = s;
    }
    __syncthreads();
    int a = tid;
    float dec_a = dec[b*128 + a];
    float gv = gvec[a];
    float wl[10];
    #pragma unroll
    for (int c = 0; c < 10; ++c) wl[c] = w_loc[c*128 + a];
    int wv = tid >> 6;
    for (int tt = 0; tt < 8; ++tt) {
      float s = enc_proj[(size_t)(b*512 + t0 + tt)*128 + a] + dec_a;
      #pragma unroll
      for (int c = 0; c < 10; ++c) s += locl[c][tt]*wl[c];
      float v = tanhf(s)*gv;
      for (int off = 32; off; off >>= 1) v += __shfl_down(v, off);
      if ((tid & 63) == 0) red[wv][tt] = v;
    }
    __syncthreads();
    if (tid < 8) {
      int t = t0 + tid;
      float ee = red[0][tid] + red[1][tid];
      int hl = hlens[b];
      e_out[b*512 + t] = (t < hl) ? ee : -1e30f;
    }
  }
}

// ---------------- softmax + att_c: 256 threads, t split over 4 waves ----------------
__global__ __launch_bounds__(256) void k_attc2(const float* __restrict__ e_buf, const float* __restrict__ hs,
                                               float* __restrict__ aw_out, float* __restrict__ xc) {
  int b = blockIdx.x >> 3, dc = blockIdx.x & 7;
  int tid = threadIdx.x;  // 256
  __shared__ float aws[512];
  __shared__ float red8[8];
  __shared__ float cred[256];
  float e0 = e_buf[b*512 + tid];
  float e1 = e_buf[b*512 + 256 + tid];
  float m = fmaxf(e0, e1);
  #pragma unroll
  for (int off = 32; off; off >>= 1) m = fmaxf(m, __shfl_xor(m, off));
  if ((tid & 63) == 0) red8[tid >> 6] = m;
  __syncthreads();
  m = fmaxf(fmaxf(red8[0], red8[1]), fmaxf(red8[2], red8[3]));
  float p0 = __expf(e0 - m), p1 = __expf(e1 - m);
  float ssum = p0 + p1;
  #pragma unroll
  for (int off = 32; off; off >>= 1) ssum += __shfl_xor(ssum, off);
  if ((tid & 63) == 0) red8[4 + (tid >> 6)] = ssum;
  __syncthreads();
  float inv = 1.0f/(red8[4] + red8[5] + red8[6] + red8[7]);
  float a0 = p0*inv, a1 = p1*inv;
  aws[tid] = a0; aws[tid + 256] = a1;
  if (dc == 0) { aw_out[b*512 + tid] = a0; aw_out[b*512 + 256 + tid] = a1; }
  __syncthreads();
  int d = dc*64 + (tid & 63), w = tid >> 6;
  const float* hp  = hs + (size_t)(b*512 + w*128)*512 + d;
  const float* awp = aws + w*128;
  float acc = 0.f;
  #pragma unroll 8
  for (int t = 0; t < 128; ++t) acc += awp[t]*hp[(size_t)t*512];
  cred[w*64 + (tid & 63)] = acc;
  __syncthreads();
  if (tid < 64)
    xc[b*768 + dc*64 + tid] = cred[tid] + cred[64 + tid] + cred[128 + tid] + cred[192 + tid];
}

// ---------------- LSTM GEMM v2: full-operand LDS staging, barrier-free weight stream ----------------
// blocks 0..255: block covers 16 j rows (4 gates x 4 u), all 32 b. thread = (b, 2 j rows).
// FP accumulation order identical to the original (k ascending, same fma expression).
// blocks 256..259 (lstm1 call only): dec = z0_new @ w_dec for the NEXT step's attention.
__global__ __launch_bounds__(256) void k_lstm2(
    const float* __restrict__ xin, int xK, const float* __restrict__ wih,
    const float* __restrict__ hin, const float* __restrict__ whh,
    const float* __restrict__ bias, float* __restrict__ cst, float* __restrict__ hnew,
    float* __restrict__ dec_out, const float* __restrict__ wdec_t) {
  __shared__ float xs[32*1028 + 4];   // ~128.6 KB: 32 rows, stride K+4 (max 1028)
  int tid = threadIdx.x;

  if (blockIdx.x >= 256) {
    // ---- dec blocks: dec = xin(=z0_new) @ w_dec ----
    for (int i = tid; i < 8192; i += 256) {
      int bb = i >> 8, kq = i & 255;
      *(float4*)(xs + bb*1028 + kq*4) = *(const float4*)(xin + (size_t)bb*1024 + kq*4);
    }
    __syncthreads();
    int e4 = blockIdx.x - 256;          // 0..3
    int b = tid & 31, ao = tid >> 5;    // 8 a-quads
    int a0 = e4*32 + ao*4;
    float s0=0.f, s1=0.f, s2=0.f, s3=0.f;
    const float4* zz = (const float4*)(xs + b*1028);
    const float4* q0 = (const float4*)(wdec_t + (size_t)(a0+0)*1024);
    const float4* q1 = (const float4*)(wdec_t + (size_t)(a0+1)*1024);
    const float4* q2 = (const float4*)(wdec_t + (size_t)(a0+2)*1024);
    const float4* q3 = (const float4*)(wdec_t + (size_t)(a0+3)*1024);
    #pragma unroll 4
    for (int k4 = 0; k4 < 256; ++k4) {
      float4 z = zz[k4];
      float4 w;
      w = q0[k4]; s0 += w.x*z.x + w.y*z.y + w.z*z.z + w.w*z.w;
      w = q1[k4]; s1 += w.x*z.x + w.y*z.y + w.z*z.z + w.w*z.w;
      w = q2[k4]; s2 += w.x*z.x + w.y*z.y + w.z*z.z + w.w*z.w;
      w = q3[k4]; s3 += w.x*z.x + w.y*z.y + w.z*z.z + w.w*z.w;
    }
    dec_out[b*128 + a0+0] = s0;
    dec_out[b*128 + a0+1] = s1;
    dec_out[b*128 + a0+2] = s2;
    dec_out[b*128 + a0+3] = s3;
    return;
  }

  int b = tid & 31, jq = tid >> 5;
  int jj0 = jq*2;
  int gate = jj0 >> 2;
  int uo0 = jj0 & 3;
  int j0 = gate*1024 + blockIdx.x*4 + uo0;
  float acc0 = bias[j0], acc1 = bias[j0 + 1];

  // ---- x part: stage all of x (32 x xK), then stream weights with no barriers ----
  {
    const int S = xK + 4;
    const int qpb = xK >> 2;
    for (int i = tid; i < 32*qpb; i += 256) {
      int bb = i / qpb, kq = i - bb*qpb;
      *(float4*)(xs + bb*S + kq*4) = *(const float4*)(xin + (size_t)bb*xK + kq*4);
    }
    __syncthreads();
    const float* w0 = wih + (size_t)j0*xK;
    const float* w1 = w0 + xK;
    const float* xrow = xs + b*S;
    #pragma unroll 8
    for (int kk = 0; kk < xK; kk += 4) {
      float4 a0 = *(const float4*)(w0 + kk);
      float4 a1 = *(const float4*)(w1 + kk);
      float4 x4 = *(const float4*)(xrow + kk);
      acc0 += a0.x*x4.x + a0.y*x4.y + a0.z*x4.z + a0.w*x4.w;
      acc1 += a1.x*x4.x + a1.y*x4.y + a1.z*x4.z + a1.w*x4.w;
    }
  }
  __syncthreads();
  // ---- h part: stage all of h (32 x 1024), then stream ----
  {
    for (int i = tid; i < 8192; i += 256) {
      int bb = i >> 8, kq = i & 255;
      *(float4*)(xs + bb*1028 + kq*4) = *(const float4*)(hin + (size_t)bb*1024 + kq*4);
    }
    __syncthreads();
    const float* v0 = whh + (size_t)j0*1024;
    const float* v1 = v0 + 1024;
    const float* xrow = xs + b*1028;
    #pragma unroll 8
    for (int kk = 0; kk < 1024; kk += 4) {
      float4 a0 = *(const float4*)(v0 + kk);
      float4 a1 = *(const float4*)(v1 + kk);
      float4 x4 = *(const float4*)(xrow + kk);
      acc0 += a0.x*x4.x + a0.y*x4.y + a0.z*x4.z + a0.w*x4.w;
      acc1 += a1.x*x4.x + a1.y*x4.y + a1.z*x4.z + a1.w*x4.w;
    }
  }
  __syncthreads();
  float* gbuf = xs;  // reuse (16*33 floats)
  gbuf[jj0*33 + b] = acc0;
  gbuf[(jj0+1)*33 + b] = acc1;
  __syncthreads();
  if (tid < 128) {
    int b2 = tid & 31, uo = tid >> 5;
    float gi = gbuf[(0*4 + uo)*33 + b2];
    float gf = gbuf[(1*4 + uo)*33 + b2];
    float gg = gbuf[(2*4 + uo)*33 + b2];
    float go = gbuf[(3*4 + uo)*33 + b2];
    int u = blockIdx.x*4 + uo;
    float c_old = cst[b2*1024 + u];
    float c_new = sigm(gf)*c_old + sigm(gi)*tanhf(gg);
    float h = sigm(go)*tanhf(c_new);
    cst[b2*1024 + u] = c_new;
    hnew[b2*1024 + u] = h;
  }
}

// ---------------- postnet conv1d (k=5, pad=2), optional fused residual+transpose ----------------
__global__ void k_conv(const float* __restrict__ in, const float* __restrict__ wk,
                       int CI, int CO, float* __restrict__ out,
                       const float* __restrict__ resid, float* __restrict__ final_out) {
  int b = blockIdx.x, coT = blockIdx.y, lT = blockIdx.z;
  int l0 = lT*64;
  int tid = threadIdx.x;
  int lq = tid & 15, coq = tid >> 4;
  __shared__ float xs[16*68];
  __shared__ float wt[64*81];
  float acc[4][4];
  #pragma unroll
  for (int m = 0; m < 4; ++m)
    #pragma unroll
    for (int li = 0; li < 4; ++li) acc[m][li] = 0.f;
  int coBase = coT*64 + coq*4;
  for (int cc0 = 0; cc0 < CI; cc0 += 16) {
    __syncthreads();
    for (int i = tid; i < 16*68; i += 256) {
      int ci = i/68, pos = i - ci*68;
      int gl = l0 - 2 + pos;
      xs[i] = (gl >= 0 && gl < 256) ? in[((size_t)b*CI + cc0 + ci)*256 + gl] : 0.f;
    }
    for (int i = tid; i < 64*80; i += 256) {
      int co_i = i/80, rem = i - co_i*80;
      int cog = coT*64 + co_i;
      float w = (cog < CO) ? wk[(size_t)cog*CI*5 + (size_t)cc0*5 + rem] : 0.f;
      wt[co_i*81 + rem] = w;
    }
    __syncthreads();
    #pragma unroll 2
    for (int ci = 0; ci < 16; ++ci) {
      float4 xa = *(const float4*)&xs[ci*68 + lq*4];
      float4 xb = *(const float4*)&xs[ci*68 + lq*4 + 4];
      float x8[8] = {xa.x, xa.y, xa.z, xa.w, xb.x, xb.y, xb.z, xb.w};
      #pragma unroll
      for (int kk = 0; kk < 5; ++kk) {
        float w0 = wt[(coq*4+0)*81 + ci*5 + kk];
        float w1 = wt[(coq*4+1)*81 + ci*5 + kk];
        float w2 = wt[(coq*4+2)*81 + ci*5 + kk];
        float w3 = wt[(coq*4+3)*81 + ci*5 + kk];
        #pragma unroll
        for (int li = 0; li < 4; ++li) {
          float xv = x8[kk + li];
          acc[0][li] += w0*xv; acc[1][li] += w1*xv;
          acc[2][li] += w2*xv; acc[3][li] += w3*xv;
        }
      }
    }
  }
  if (final_out) {
    #pragma unroll
    for (int m = 0; m < 4; ++m) {
      int co = coBase + m;
      if (co < CO) {
        #pragma unroll
        for (int li = 0; li < 4; ++li) {
          int l = l0 + lq*4 + li;
          final_out[(size_t)(b*256 + l)*80 + co] =
              acc[m][li] + resid[((size_t)b*80 + co)*256 + l];
        }
      }
    }
  } else {
    #pragma unroll
    for (int m = 0; m < 4; ++m) {
      int co = coBase + m;
      if (co < CO) {
        float4 v = {acc[m][0], acc[m][1], acc[m][2], acc[m][3]};
        *(float4*)&out[((size_t)b*CO + co)*256 + l0 + lq*4] = v;
      }
    }
  }
}

// ---------------- BN train-mode stats (per channel over B,L) ----------------
__global__ void k_bnstats(const float* __restrict__ x, const float* __restrict__ g,
                          const float* __restrict__ bt, float* __restrict__ scale,
                          float* __restrict__ shift) {
  int c = blockIdx.x;
  int tid = threadIdx.x;  // 256
  float s = 0.f, s2 = 0.f;
  for (int i = tid; i < 8192; i += 256) {
    int bb = i >> 8, l = i & 255;
    float v = x[((size_t)bb*512 + c)*256 + l];
    s += v; s2 += v*v;
  }
  __shared__ float rs[256], rs2[256];
  rs[tid] = s; rs2[tid] = s2;
  __syncthreads();
  for (int st = 128; st; st >>= 1) {
    if (tid < st) { rs[tid] += rs[tid + st]; rs2[tid] += rs2[tid + st]; }
    __syncthreads();
  }
  if (tid == 0) {
    float m = rs[0]/8192.f;
    float var = rs2[0]/8192.f - m*m;
    float inv = rsqrtf(var + 1e-5f);
    float sc = g[c]*inv;
    scale[c] = sc;
    shift[c] = bt[c] - m*sc;
  }
}

__global__ void k_bnapply(float* __restrict__ x, const float* __restrict__ scale,
                          const float* __restrict__ shift) {
  int i = blockIdx.x*256 + threadIdx.x;
  if (i < 32*512*256) {
    int c = (i >> 8) & 511;
    x[i] = tanhf(scale[c]*x[i] + shift[c]);
  }
}

// ---------------- launcher ----------------
extern "C" void kernel_launch(void* const* d_in, const int* in_sizes, int n_in,
                              void* d_out, int out_size, void* d_ws, size_t ws_size,
                              hipStream_t stream) {
  const float* hs       = (const float*)d_in[0];
  const int*   hlens    = (const int*)d_in[1];
  const int*   ylens    = (const int*)d_in[3];
  const float* w_enc    = (const float*)d_in[4];
  const float* b_enc    = (const float*)d_in[5];
  const float* w_dec    = (const float*)d_in[6];
  const float* loc_k    = (const float*)d_in[7];
  const float* w_loc    = (const float*)d_in[8];
  const float* gvec     = (const float*)d_in[9];
  const float* pre_w1   = (const float*)d_in[10];
  const float* pre_b1   = (const float*)d_in[11];
  const float* pre_w2   = (const float*)d_in[12];
  const float* pre_b2   = (const float*)d_in[13];
  const float* l0_wih   = (const float*)d_in[14];
  const float* l0_whh   = (const float*)d_in[15];
  const float* l0_b     = (const float*)d_in[16];
  const float* l1_wih   = (const float*)d_in[17];
  const float* l1_whh   = (const float*)d_in[18];
  const float* l1_b     = (const float*)d_in[19];
  const float* feat_w   = (const float*)d_in[20];
  const float* feat_b   = (const float*)d_in[21];
  const float* prob_w   = (const float*)d_in[22];
  const float* prob_b   = (const float*)d_in[23];
  const float* post_k1  = (const float*)d_in[24];
  const float* post_k2  = (const float*)d_in[25];
  const float* post_k3  = (const float*)d_in[26];
  const float* post_k4  = (const float*)d_in[27];
  const float* post_k5  = (const float*)d_in[28];
  const float* bn_g1 = (const float*)d_in[29]; const float* bn_b1 = (const float*)d_in[30];
  const float* bn_g2 = (const float*)d_in[31]; const float* bn_b2 = (const float*)d_in[32];
  const float* bn_g3 = (const float*)d_in[33]; const float* bn_b3 = (const float*)d_in[34];
  const float* bn_g4 = (const float*)d_in[35]; const float* bn_b4 = (const float*)d_in[36];

  float* ws = (float*)d_ws;
  float* enc_proj = ws + 0;
  float* aw       = ws + 2097152;
  float* e        = ws + 2113536;
  float* dec      = ws + 2129920;
  float* xc       = ws + 2134016;
  float* z0       = ws + 2158592;   // 2 x 32768
  float* z1       = ws + 2224128;   // 2 x 32768
  float* c0       = ws + 2289664;
  float* c1       = ws + 2322432;
  float* fw_t     = ws + 2355200;
  float* wdec_t   = ws + 2437120;
  float* outs_ws  = ws + 2568192;
  float* pn1      = ws + 3223552;
  float* pn2      = ws + 7417856;
  float* bsc      = ws + 11612160;
  float* bsh      = ws + 11612672;

  float* outp  = (float*)d_out;            // outs (B,L,80)
  float* probp = outp + 655360;            // probs (B,L)

  k_init<<<1041, 256, 0, stream>>>(z0, c0, z1, c1, aw, fw_t, wdec_t, dec,
                                   feat_w, w_dec, hlens, ylens, outp);
  k_encproj<<<dim3(32, 32), 256, 0, stream>>>(hs, w_enc, b_enc, enc_proj);

  for (int s = 0; s < 256; ++s) {
    int p = s & 1;
    float* z0r = z0 + p*32768;  float* z0w = z0 + (1-p)*32768;
    float* z1r = z1 + p*32768;  float* z1w = z1 + (1-p)*32768;
    // step_a (feat/prob/prenet) + att_e in ONE dispatch (dec comes from prev lstm1)
    k_ae<<<2080, 128, 0, stream>>>(z1r, fw_t, feat_b, prob_w, prob_b,
                                   pre_w1, pre_b1, pre_w2, pre_b2,
                                   outs_ws, probp, xc,
                                   aw, loc_k, w_loc, gvec, enc_proj, dec, hlens, e,
                                   s - 1, 0);
    k_attc2<<<256, 256, 0, stream>>>(e, hs, aw, xc);
    k_lstm2<<<256, 256, 0, stream>>>(xc, 768, l0_wih, z0r, l0_whh, l0_b, c0, z0w,
                                     nullptr, nullptr);
    k_lstm2<<<260, 256, 0, stream>>>(z0w, 1024, l1_wih, z1r, l1_whh, l1_b, c1, z1w,
                                     dec, wdec_t);
  }
  // final out/prob from z1 (after 256 steps, current z1 is parity 0)
  k_ae<<<32, 128, 0, stream>>>(z1, fw_t, feat_b, prob_w, prob_b,
                               pre_w1, pre_b1, pre_w2, pre_b2,
                               outs_ws, probp, xc,
                               aw, loc_k, w_loc, gvec, enc_proj, dec, hlens, e,
                               255, 1);

  // postnet
  k_conv<<<dim3(32, 8, 4), 256, 0, stream>>>(outs_ws, post_k1, 80, 512, pn1, nullptr, nullptr);
  k_bnstats<<<512, 256, 0, stream>>>(pn1, bn_g1, bn_b1, bsc, bsh);
  k_bnapply<<<16384, 256, 0, stream>>>(pn1, bsc, bsh);

  k_conv<<<dim3(32, 8, 4), 256, 0, stream>>>(pn1, post_k2, 512, 512, pn2, nullptr, nullptr);
  k_bnstats<<<512, 256, 0, stream>>>(pn2, bn_g2, bn_b2, bsc, bsh);
  k_bnapply<<<16384, 256, 0, stream>>>(pn2, bsc, bsh);

  k_conv<<<dim3(32, 8, 4), 256, 0, stream>>>(pn2, post_k3, 512, 512, pn1, nullptr, nullptr);
  k_bnstats<<<512, 256, 0, stream>>>(pn1, bn_g3, bn_b3, bsc, bsh);
  k_bnapply<<<16384, 256, 0, stream>>>(pn1, bsc, bsh);

  k_conv<<<dim3(32, 8, 4), 256, 0, stream>>>(pn1, post_k4, 512, 512, pn2, nullptr, nullptr);
  k_bnstats<<<512, 256, 0, stream>>>(pn2, bn_g4, bn_b4, bsc, bsh);
  k_bnapply<<<16384, 256, 0, stream>>>(pn2, bsc, bsh);

  k_conv<<<dim3(32, 2, 4), 256, 0, stream>>>(pn2, post_k5, 512, 80, pn1, outs_ws, outp);
}

// Round 3
// 56130.060 us; speedup vs baseline: 2.2535x; 1.1111x over previous
//
#include <hip/hip_runtime.h>
#include <math.h>

// Problem constants
// B=32, T=512, IDIM=512, ODIM=80, L=256, DUNITS=1024, ATT=128, ACH=10, AK=31, PRE=256, POST=512

__device__ __forceinline__ float sigm(float x){ return 1.0f/(1.0f+__expf(-x)); }

// ---------------- workspace layout (floats) ----------------
// OFF_ENC  : 0         (2097152)  enc_proj (B,T,ATT)
// OFF_AW   : 2097152   (16384)    aw (B,T)
// OFF_E    : 2113536   (16384)    e  (B,T)
// OFF_DEC  : 2129920   (4096)     (unused now)
// OFF_XC   : 2134016   (24576)    xc (B,768)  [att_c | prenet]
// OFF_Z0   : 2158592   (65536)    z0 ping-pong (2,B,1024)
// OFF_Z1   : 2224128   (65536)    z1 ping-pong
// OFF_C0   : 2289664   (32768)
// OFF_C1   : 2322432   (32768)
// OFF_FWT  : 2355200   (81920)    feat_w transposed (80,1024)
// OFF_WDT  : 2437120   (131072)   w_dec transposed (128,1024)
// OFF_OUTS : 2568192   (655360)   outs_ws (B,80,L)
// OFF_PN1  : 3223552   (4194304)  postnet buf (B,512,L)
// OFF_PN2  : 7417856   (4194304)  [first 32768 double as dec_part[8][32][128] during loop]
// OFF_BSC  : 11612160  (512)
// OFF_BSH  : 11612672  (512)

// ---------------- init: zero states, aw0, weight transposes, ylens, dec_part ----------------
__global__ void k_init(float* __restrict__ z0, float* __restrict__ c0,
                       float* __restrict__ z1, float* __restrict__ c1,
                       float* __restrict__ aw, float* __restrict__ fw_t, float* __restrict__ wdec_t,
                       const float* __restrict__ feat_w, const float* __restrict__ w_dec,
                       const int* __restrict__ hlens, const int* __restrict__ ylens,
                       float* __restrict__ d_out, float* __restrict__ dec_part) {
  int i = blockIdx.x*256 + threadIdx.x;
  if (i < 32768) {
    z0[i]=0.f; c0[i]=0.f; z1[i]=0.f; c1[i]=0.f;
  } else if (i < 49152) {
    int j = i - 32768; int b = j >> 9; int t = j & 511;
    int hl = hlens[b];
    aw[j] = (t < hl) ? 1.0f/(float)hl : 0.f;
  } else if (i < 131072) {
    int j = i - 49152; int od = j >> 10, k = j & 1023;
    fw_t[j] = feat_w[k*80 + od];
  } else if (i < 262144) {
    int j = i - 131072; int a = j >> 10, k = j & 1023;
    wdec_t[j] = w_dec[k*128 + a];
  } else if (i < 262176) {
    int b = i - 262144;
    d_out[663552 + b] = (float)ylens[b];
  } else if (i < 294944) {
    dec_part[i - 262176] = 0.f;   // dec partials for step 0 (z0 = 0)
  }
}

// ---------------- enc_proj = hs @ w_enc + b_enc ----------------
__global__ void k_encproj(const float* __restrict__ hs, const float* __restrict__ w_enc,
                          const float* __restrict__ b_enc, float* __restrict__ enc_proj) {
  __shared__ float hsl[16*512];
  int b = blockIdx.x, t0 = blockIdx.y*16;
  int tid = threadIdx.x;  // 256
  for (int i = tid; i < 16*512; i += 256)
    hsl[i] = hs[(size_t)(b*512 + t0 + (i>>9))*512 + (i&511)];
  __syncthreads();
  int a = tid & 127, tq = tid >> 7;
  float acc[8];
  #pragma unroll
  for (int u=0;u<8;++u) acc[u]=0.f;
  for (int d=0; d<512; ++d) {
    float w = w_enc[d*128 + a];
    #pragma unroll
    for (int u=0;u<8;++u) acc[u] += hsl[(tq*8+u)*512 + d]*w;
  }
  float be = b_enc[a];
  #pragma unroll
  for (int u=0;u<8;++u)
    enc_proj[(size_t)(b*512 + t0 + tq*8 + u)*128 + a] = acc[u] + be;
}

// ---------------- LSTM body: chunked LDS staging (KC=256), identical k-ascending FP order ----------------
// block = 16 j rows (4 gates x 4 u, utile = bid), thread = (b, 2 j rows)
__device__ __forceinline__ void lstm_body(
    const float* __restrict__ xin, int xK, const float* __restrict__ wih,
    const float* __restrict__ hin, const float* __restrict__ whh,
    const float* __restrict__ bias, float* __restrict__ cst, float* __restrict__ hnew,
    int bid, int tid, float* __restrict__ xs, float* __restrict__ hb) {
  int b = tid & 31, jq = tid >> 5;
  int jj0 = jq*2;
  int gate = jj0 >> 2;
  int uo0 = jj0 & 3;
  int j0 = gate*1024 + bid*4 + uo0;
  float acc0 = bias[j0], acc1 = bias[j0 + 1];

  const float* w0 = wih + (size_t)j0*xK;
  const float* w1 = w0 + xK;
  for (int c0 = 0; c0 < xK; c0 += 256) {
    __syncthreads();
    for (int i = tid; i < 2048; i += 256) {
      int bb = i >> 6, kq = i & 63;
      *(float4*)(xs + bb*260 + kq*4) = *(const float4*)(xin + (size_t)bb*xK + c0 + kq*4);
    }
    __syncthreads();
    const float* xrow = xs + b*260;
    #pragma unroll 8
    for (int kk = 0; kk < 256; kk += 4) {
      float4 a0 = *(const float4*)(w0 + c0 + kk);
      float4 a1 = *(const float4*)(w1 + c0 + kk);
      float4 x4 = *(const float4*)(xrow + kk);
      acc0 += a0.x*x4.x + a0.y*x4.y + a0.z*x4.z + a0.w*x4.w;
      acc1 += a1.x*x4.x + a1.y*x4.y + a1.z*x4.z + a1.w*x4.w;
    }
  }
  const float* v0 = whh + (size_t)j0*1024;
  const float* v1 = v0 + 1024;
  for (int c0 = 0; c0 < 1024; c0 += 256) {
    __syncthreads();
    for (int i = tid; i < 2048; i += 256) {
      int bb = i >> 6, kq = i & 63;
      *(float4*)(xs + bb*260 + kq*4) = *(const float4*)(hin + (size_t)bb*1024 + c0 + kq*4);
    }
    __syncthreads();
    const float* xrow = xs + b*260;
    #pragma unroll 8
    for (int kk = 0; kk < 256; kk += 4) {
      float4 a0 = *(const float4*)(v0 + c0 + kk);
      float4 a1 = *(const float4*)(v1 + c0 + kk);
      float4 x4 = *(const float4*)(xrow + kk);
      acc0 += a0.x*x4.x + a0.y*x4.y + a0.z*x4.z + a0.w*x4.w;
      acc1 += a1.x*x4.x + a1.y*x4.y + a1.z*x4.z + a1.w*x4.w;
    }
  }
  __syncthreads();
  float* gbuf = xs;  // 16*33 floats
  gbuf[jj0*33 + b] = acc0;
  gbuf[(jj0+1)*33 + b] = acc1;
  __syncthreads();
  if (tid < 128) {
    int b2 = tid & 31, uo = tid >> 5;
    float gi = gbuf[(0*4 + uo)*33 + b2];
    float gf = gbuf[(1*4 + uo)*33 + b2];
    float gg = gbuf[(2*4 + uo)*33 + b2];
    float go = gbuf[(3*4 + uo)*33 + b2];
    int u = bid*4 + uo;
    float c_old = cst[b2*1024 + u];
    float c_new = sigm(gf)*c_old + sigm(gi)*tanhf(gg);
    float h = sigm(go)*tanhf(c_new);
    cst[b2*1024 + u] = c_new;
    hnew[b2*1024 + u] = h;
    if (hb) hb[uo*32 + b2] = h;
  }
}

// ---------------- D1: softmax+context (blocks 0..255) | feat/prob/prenet + dec_part zero (256..287) ----------------
__global__ __launch_bounds__(256) void k_d1(
    const float* __restrict__ z1_rd, const float* __restrict__ fw_t, const float* __restrict__ feat_b,
    const float* __restrict__ prob_w, const float* __restrict__ prob_b,
    const float* __restrict__ pre_w1, const float* __restrict__ pre_b1,
    const float* __restrict__ pre_w2, const float* __restrict__ pre_b2,
    float* __restrict__ outs_ws, float* __restrict__ probs_out, float* __restrict__ xc,
    const float* __restrict__ e_buf, const float* __restrict__ hs,
    float* __restrict__ aw_out, float* __restrict__ dec_part,
    int store_idx, int mode) {
  __shared__ float sm[8320];
  int tid = threadIdx.x;  // 256
  if (blockIdx.x < 256) {
    if (mode == 1) return;
    // softmax over e (redundant per b) + context chunk
    int b = blockIdx.x >> 3, dc = blockIdx.x & 7;
    float* aws  = sm;        // 512
    float* red8 = sm + 512;  // 8
    float* cred = sm + 520;  // 256
    float e0 = e_buf[b*512 + tid];
    float e1 = e_buf[b*512 + 256 + tid];
    float m = fmaxf(e0, e1);
    #pragma unroll
    for (int off = 32; off; off >>= 1) m = fmaxf(m, __shfl_xor(m, off));
    if ((tid & 63) == 0) red8[tid >> 6] = m;
    __syncthreads();
    m = fmaxf(fmaxf(red8[0], red8[1]), fmaxf(red8[2], red8[3]));
    float p0 = __expf(e0 - m), p1 = __expf(e1 - m);
    float ssum = p0 + p1;
    #pragma unroll
    for (int off = 32; off; off >>= 1) ssum += __shfl_xor(ssum, off);
    if ((tid & 63) == 0) red8[4 + (tid >> 6)] = ssum;
    __syncthreads();
    float inv = 1.0f/(red8[4] + red8[5] + red8[6] + red8[7]);
    float a0 = p0*inv, a1 = p1*inv;
    aws[tid] = a0; aws[tid + 256] = a1;
    if (dc == 0) { aw_out[b*512 + tid] = a0; aw_out[b*512 + 256 + tid] = a1; }
    __syncthreads();
    int d = dc*64 + (tid & 63), w = tid >> 6;
    const float* hp  = hs + (size_t)(b*512 + w*128)*512 + d;
    const float* awp = aws + w*128;
    float acc = 0.f;
    #pragma unroll 8
    for (int t = 0; t < 128; ++t) acc += awp[t]*hp[(size_t)t*512];
    cred[w*64 + (tid & 63)] = acc;
    __syncthreads();
    if (tid < 64)
      xc[b*768 + dc*64 + tid] = cred[tid] + cred[64 + tid] + cred[128 + tid] + cred[192 + tid];
  } else {
    int b = blockIdx.x - 256;
    if (tid < 128) {
      #pragma unroll
      for (int sl = 0; sl < 8; ++sl) dec_part[sl*4096 + b*128 + tid] = 0.f;
    }
    float* zs   = sm;         // 1024
    float* prev = sm + 1024;  // 80
    float* h1s  = sm + 1104;  // 256
    for (int i = tid; i < 1024; i += 256) zs[i] = z1_rd[b*1024 + i];
    __syncthreads();
    if (tid < 80) {
      const float4* wp = (const float4*)(fw_t + tid*1024);
      float acc = feat_b[tid];
      for (int k4 = 0; k4 < 256; ++k4) {
        float4 w = wp[k4];
        acc += zs[k4*4+0]*w.x + zs[k4*4+1]*w.y + zs[k4*4+2]*w.z + zs[k4*4+3]*w.w;
      }
      prev[tid] = acc;
      if (store_idx >= 0) outs_ws[(b*80 + tid)*256 + store_idx] = acc;
    } else if (tid == 80) {
      const float4* wp = (const float4*)prob_w;
      float acc = prob_b[0];
      for (int k4 = 0; k4 < 256; ++k4) {
        float4 w = wp[k4];
        acc += zs[k4*4+0]*w.x + zs[k4*4+1]*w.y + zs[k4*4+2]*w.z + zs[k4*4+3]*w.w;
      }
      if (store_idx >= 0) probs_out[b*256 + store_idx] = acc;
    }
    if (mode == 1) return;
    __syncthreads();
    // prenet layer 1: (80 -> 256)
    {
      float acc = pre_b1[tid];
      for (int k = 0; k < 80; ++k) acc += prev[k]*pre_w1[k*256 + tid];
      h1s[tid] = fmaxf(acc, 0.f);
    }
    __syncthreads();
    // prenet layer 2: (256 -> 256)
    {
      float acc = pre_b2[tid];
      for (int k = 0; k < 256; ++k) acc += h1s[k]*pre_w2[k*256 + tid];
      xc[b*768 + 512 + tid] = fmaxf(acc, 0.f);
    }
  }
}

// ---------------- D2: lstm0 + fused dec-partial epilogue ----------------
__global__ __launch_bounds__(256) void k_d2(
    const float* __restrict__ xc, const float* __restrict__ wih,
    const float* __restrict__ z0r, const float* __restrict__ whh,
    const float* __restrict__ bias, float* __restrict__ c0, float* __restrict__ z0w,
    const float* __restrict__ wdec_t, float* __restrict__ dec_part) {
  __shared__ float sm[8320];
  int tid = threadIdx.x, bid = blockIdx.x;
  lstm_body(xc, 768, wih, z0r, whh, bias, c0, z0w, bid, tid, sm, sm + 528);
  __syncthreads();
  // dec partial: dec[b][a] += sum_{uo<4} h[b][bid*4+uo] * wdec_t[a][bid*4+uo]
  int b = tid & 31, aq = tid >> 5;
  float h0 = sm[528 + 0*32 + b];
  float h1 = sm[528 + 1*32 + b];
  float h2 = sm[528 + 2*32 + b];
  float h3 = sm[528 + 3*32 + b];
  float* dp = dec_part + (bid & 7)*4096 + b*128;
  #pragma unroll
  for (int ai = 0; ai < 16; ++ai) {
    int a = aq*16 + ai;
    float4 w = *(const float4*)(wdec_t + (size_t)a*1024 + bid*4);
    atomicAdd(dp + a, w.x*h0 + w.y*h1 + w.z*h2 + w.w*h3);
  }
}

// ---------------- D3: lstm1 (blocks 0..255) | att_e for next step (blocks 256..1279) ----------------
__global__ __launch_bounds__(256) void k_d3(
    const float* __restrict__ z0w, const float* __restrict__ wih,
    const float* __restrict__ z1r, const float* __restrict__ whh,
    const float* __restrict__ bias, float* __restrict__ c1, float* __restrict__ z1w,
    const float* __restrict__ aw, const float* __restrict__ loc_k,
    const float* __restrict__ w_loc, const float* __restrict__ gvec,
    const float* __restrict__ enc_proj, const float* __restrict__ dec_part,
    const int* __restrict__ hlens, float* __restrict__ e_out, int mode) {
  __shared__ float sm[8320];
  int tid = threadIdx.x;  // 256
  if (blockIdx.x < 256) {
    if (mode == 1) return;
    lstm_body(z0w, 1024, wih, z1r, whh, bias, c1, z1w, blockIdx.x, tid, sm, nullptr);
    return;
  }
  // ---- att_e: 16 t positions per block ----
  int bx = blockIdx.x - 256;
  int b = bx >> 5, t0 = (bx & 31)*16;
  float* awin = sm;        // 46
  float* locl = sm + 48;   // 160: locl[c*16+tt]
  float* red  = sm + 240;  // 32
  if (tid < 46) {
    int idx = t0 - 15 + tid;
    awin[tid] = (idx >= 0 && idx < 512) ? aw[b*512 + idx] : 0.f;
  }
  __syncthreads();
  if (tid < 160) {
    int c = tid >> 4, tt = tid & 15;
    float s = 0.f;
    #pragma unroll
    for (int k = 0; k < 31; ++k) s += awin[tt + k]*loc_k[c*31 + k];
    locl[c*16 + tt] = s;
  }
  __syncthreads();
  int a = tid & 127, th = tid >> 7, wv = tid >> 6;
  float dec_a = 0.f;
  #pragma unroll
  for (int sl = 0; sl < 8; ++sl) dec_a += dec_part[sl*4096 + b*128 + a];
  float gv = gvec[a];
  float wl[10];
  #pragma unroll
  for (int c = 0; c < 10; ++c) wl[c] = w_loc[c*128 + a];
  #pragma unroll
  for (int tt = 0; tt < 8; ++tt) {
    int tl = th*8 + tt;
    float s = enc_proj[(size_t)(b*512 + t0 + tl)*128 + a] + dec_a;
    #pragma unroll
    for (int c = 0; c < 10; ++c) s += locl[c*16 + tl]*wl[c];
    float v = tanhf(s)*gv;
    #pragma unroll
    for (int off = 32; off; off >>= 1) v += __shfl_down(v, off);
    if ((tid & 63) == 0) red[wv*8 + tt] = v;
  }
  __syncthreads();
  if (tid < 16) {
    int t = t0 + tid;
    float ee = (tid < 8) ? (red[tid] + red[8 + tid])
                         : (red[16 + (tid - 8)] + red[24 + (tid - 8)]);
    e_out[b*512 + t] = (t < hlens[b]) ? ee : -1e30f;
  }
}

// ---------------- postnet conv1d (k=5, pad=2), optional fused residual+transpose ----------------
__global__ void k_conv(const float* __restrict__ in, const float* __restrict__ wk,
                       int CI, int CO, float* __restrict__ out,
                       const float* __restrict__ resid, float* __restrict__ final_out) {
  int b = blockIdx.x, coT = blockIdx.y, lT = blockIdx.z;
  int l0 = lT*64;
  int tid = threadIdx.x;
  int lq = tid & 15, coq = tid >> 4;
  __shared__ float xs[16*68];
  __shared__ float wt[64*81];
  float acc[4][4];
  #pragma unroll
  for (int m = 0; m < 4; ++m)
    #pragma unroll
    for (int li = 0; li < 4; ++li) acc[m][li] = 0.f;
  int coBase = coT*64 + coq*4;
  for (int cc0 = 0; cc0 < CI; cc0 += 16) {
    __syncthreads();
    for (int i = tid; i < 16*68; i += 256) {
      int ci = i/68, pos = i - ci*68;
      int gl = l0 - 2 + pos;
      xs[i] = (gl >= 0 && gl < 256) ? in[((size_t)b*CI + cc0 + ci)*256 + gl] : 0.f;
    }
    for (int i = tid; i < 64*80; i += 256) {
      int co_i = i/80, rem = i - co_i*80;
      int cog = coT*64 + co_i;
      float w = (cog < CO) ? wk[(size_t)cog*CI*5 + (size_t)cc0*5 + rem] : 0.f;
      wt[co_i*81 + rem] = w;
    }
    __syncthreads();
    #pragma unroll 2
    for (int ci = 0; ci < 16; ++ci) {
      float4 xa = *(const float4*)&xs[ci*68 + lq*4];
      float4 xb = *(const float4*)&xs[ci*68 + lq*4 + 4];
      float x8[8] = {xa.x, xa.y, xa.z, xa.w, xb.x, xb.y, xb.z, xb.w};
      #pragma unroll
      for (int kk = 0; kk < 5; ++kk) {
        float w0 = wt[(coq*4+0)*81 + ci*5 + kk];
        float w1 = wt[(coq*4+1)*81 + ci*5 + kk];
        float w2 = wt[(coq*4+2)*81 + ci*5 + kk];
        float w3 = wt[(coq*4+3)*81 + ci*5 + kk];
        #pragma unroll
        for (int li = 0; li < 4; ++li) {
          float xv = x8[kk + li];
          acc[0][li] += w0*xv; acc[1][li] += w1*xv;
          acc[2][li] += w2*xv; acc[3][li] += w3*xv;
        }
      }
    }
  }
  if (final_out) {
    #pragma unroll
    for (int m = 0; m < 4; ++m) {
      int co = coBase + m;
      if (co < CO) {
        #pragma unroll
        for (int li = 0; li < 4; ++li) {
          int l = l0 + lq*4 + li;
          final_out[(size_t)(b*256 + l)*80 + co] =
              acc[m][li] + resid[((size_t)b*80 + co)*256 + l];
        }
      }
    }
  } else {
    #pragma unroll
    for (int m = 0; m < 4; ++m) {
      int co = coBase + m;
      if (co < CO) {
        float4 v = {acc[m][0], acc[m][1], acc[m][2], acc[m][3]};
        *(float4*)&out[((size_t)b*CO + co)*256 + l0 + lq*4] = v;
      }
    }
  }
}

// ---------------- BN train-mode stats (per channel over B,L) ----------------
__global__ void k_bnstats(const float* __restrict__ x, const float* __restrict__ g,
                          const float* __restrict__ bt, float* __restrict__ scale,
                          float* __restrict__ shift) {
  int c = blockIdx.x;
  int tid = threadIdx.x;  // 256
  float s = 0.f, s2 = 0.f;
  for (int i = tid; i < 8192; i += 256) {
    int bb = i >> 8, l = i & 255;
    float v = x[((size_t)bb*512 + c)*256 + l];
    s += v; s2 += v*v;
  }
  __shared__ float rs[256], rs2[256];
  rs[tid] = s; rs2[tid] = s2;
  __syncthreads();
  for (int st = 128; st; st >>= 1) {
    if (tid < st) { rs[tid] += rs[tid + st]; rs2[tid] += rs2[tid + st]; }
    __syncthreads();
  }
  if (tid == 0) {
    float m = rs[0]/8192.f;
    float var = rs2[0]/8192.f - m*m;
    float inv = rsqrtf(var + 1e-5f);
    float sc = g[c]*inv;
    scale[c] = sc;
    shift[c] = bt[c] - m*sc;
  }
}

__global__ void k_bnapply(float* __restrict__ x, const float* __restrict__ scale,
                          const float* __restrict__ shift) {
  int i = blockIdx.x*256 + threadIdx.x;
  if (i < 32*512*256) {
    int c = (i >> 8) & 511;
    x[i] = tanhf(scale[c]*x[i] + shift[c]);
  }
}

// ---------------- launcher ----------------
extern "C" void kernel_launch(void* const* d_in, const int* in_sizes, int n_in,
                              void* d_out, int out_size, void* d_ws, size_t ws_size,
                              hipStream_t stream) {
  const float* hs       = (const float*)d_in[0];
  const int*   hlens    = (const int*)d_in[1];
  const int*   ylens    = (const int*)d_in[3];
  const float* w_enc    = (const float*)d_in[4];
  const float* b_enc    = (const float*)d_in[5];
  const float* w_dec    = (const float*)d_in[6];
  const float* loc_k    = (const float*)d_in[7];
  const float* w_loc    = (const float*)d_in[8];
  const float* gvec     = (const float*)d_in[9];
  const float* pre_w1   = (const float*)d_in[10];
  const float* pre_b1   = (const float*)d_in[11];
  const float* pre_w2   = (const float*)d_in[12];
  const float* pre_b2   = (const float*)d_in[13];
  const float* l0_wih   = (const float*)d_in[14];
  const float* l0_whh   = (const float*)d_in[15];
  const float* l0_b     = (const float*)d_in[16];
  const float* l1_wih   = (const float*)d_in[17];
  const float* l1_whh   = (const float*)d_in[18];
  const float* l1_b     = (const float*)d_in[19];
  const float* feat_w   = (const float*)d_in[20];
  const float* feat_b   = (const float*)d_in[21];
  const float* prob_w   = (const float*)d_in[22];
  const float* prob_b   = (const float*)d_in[23];
  const float* post_k1  = (const float*)d_in[24];
  const float* post_k2  = (const float*)d_in[25];
  const float* post_k3  = (const float*)d_in[26];
  const float* post_k4  = (const float*)d_in[27];
  const float* post_k5  = (const float*)d_in[28];
  const float* bn_g1 = (const float*)d_in[29]; const float* bn_b1 = (const float*)d_in[30];
  const float* bn_g2 = (const float*)d_in[31]; const float* bn_b2 = (const float*)d_in[32];
  const float* bn_g3 = (const float*)d_in[33]; const float* bn_b3 = (const float*)d_in[34];
  const float* bn_g4 = (const float*)d_in[35]; const float* bn_b4 = (const float*)d_in[36];

  float* ws = (float*)d_ws;
  float* enc_proj = ws + 0;
  float* aw       = ws + 2097152;
  float* e        = ws + 2113536;
  float* xc       = ws + 2134016;
  float* z0       = ws + 2158592;   // 2 x 32768
  float* z1       = ws + 2224128;   // 2 x 32768
  float* c0       = ws + 2289664;
  float* c1       = ws + 2322432;
  float* fw_t     = ws + 2355200;
  float* wdec_t   = ws + 2437120;
  float* outs_ws  = ws + 2568192;
  float* pn1      = ws + 3223552;
  float* pn2      = ws + 7417856;
  float* bsc      = ws + 11612160;
  float* bsh      = ws + 11612672;
  float* dec_part = pn2;            // [8][32][128], pn2 unused until postnet

  float* outp  = (float*)d_out;            // outs (B,L,80)
  float* probp = outp + 655360;            // probs (B,L)

  k_init<<<1153, 256, 0, stream>>>(z0, c0, z1, c1, aw, fw_t, wdec_t,
                                   feat_w, w_dec, hlens, ylens, outp, dec_part);
  k_encproj<<<dim3(32, 32), 256, 0, stream>>>(hs, w_enc, b_enc, enc_proj);
  // prologue: e(0) from aw0 and dec=0 (att_e only)
  k_d3<<<1280, 256, 0, stream>>>(z0, l1_wih, z1, l1_whh, l1_b, c1, z1,
                                 aw, loc_k, w_loc, gvec, enc_proj, dec_part, hlens, e, 1);

  for (int s = 0; s < 256; ++s) {
    int p = s & 1;
    float* z0r = z0 + p*32768;  float* z0w = z0 + (1-p)*32768;
    float* z1r = z1 + p*32768;  float* z1w = z1 + (1-p)*32768;
    k_d1<<<288, 256, 0, stream>>>(z1r, fw_t, feat_b, prob_w, prob_b,
                                  pre_w1, pre_b1, pre_w2, pre_b2,
                                  outs_ws, probp, xc, e, hs, aw, dec_part,
                                  s - 1, 0);
    k_d2<<<256, 256, 0, stream>>>(xc, l0_wih, z0r, l0_whh, l0_b, c0, z0w,
                                  wdec_t, dec_part);
    k_d3<<<1280, 256, 0, stream>>>(z0w, l1_wih, z1r, l1_whh, l1_b, c1, z1w,
                                   aw, loc_k, w_loc, gvec, enc_proj, dec_part, hlens, e, 0);
  }
  // tail: outs/probs idx 255 from final z1 (parity 0)
  k_d1<<<288, 256, 0, stream>>>(z1, fw_t, feat_b, prob_w, prob_b,
                                pre_w1, pre_b1, pre_w2, pre_b2,
                                outs_ws, probp, xc, e, hs, aw, dec_part,
                                255, 1);

  // postnet
  k_conv<<<dim3(32, 8, 4), 256, 0, stream>>>(outs_ws, post_k1, 80, 512, pn1, nullptr, nullptr);
  k_bnstats<<<512, 256, 0, stream>>>(pn1, bn_g1, bn_b1, bsc, bsh);
  k_bnapply<<<16384, 256, 0, stream>>>(pn1, bsc, bsh);

  k_conv<<<dim3(32, 8, 4), 256, 0, stream>>>(pn1, post_k2, 512, 512, pn2, nullptr, nullptr);
  k_bnstats<<<512, 256, 0, stream>>>(pn2, bn_g2, bn_b2, bsc, bsh);
  k_bnapply<<<16384, 256, 0, stream>>>(pn2, bsc, bsh);

  k_conv<<<dim3(32, 8, 4), 256, 0, stream>>>(pn2, post_k3, 512, 512, pn1, nullptr, nullptr);
  k_bnstats<<<512, 256, 0, stream>>>(pn1, bn_g3, bn_b3, bsc, bsh);
  k_bnapply<<<16384, 256, 0, stream>>>(pn1, bsc, bsh);

  k_conv<<<dim3(32, 8, 4), 256, 0, stream>>>(pn1, post_k4, 512, 512, pn2, nullptr, nullptr);
  k_bnstats<<<512, 256, 0, stream>>>(pn2, bn_g4, bn_b4, bsc, bsh);
  k_bnapply<<<16384, 256, 0, stream>>>(pn2, bsc, bsh);

  k_conv<<<dim3(32, 2, 4), 256, 0, stream>>>(pn2, post_k5, 512, 80, pn1, outs_ws, outp);
}